// Round 15
// baseline (149.703 us; speedup 1.0000x reference)
//
#include <hip/hip_runtime.h>
#include <hip/hip_bf16.h>
#include <cstdint>
#include <cstddef>

// B=4, C=128, L=4096, H=4 (hd=32), GROUPS=32, EPS=1e-5
// gn_stats -> MFMA qkv (gn inline) -> MFMA flash attention (128-q blocks, s-SPLIT x2:
// unnormalized fp32 partials + l partials; exact combine) -> combine -> MFMA proj.
// Dtype detected per-block via wave-0 ballot.
//
// ws layout (bytes):
//   wq_b  bf16 49,152   @ 0
//   wp_b  bf16 16,384   @ 98,304
//   bp_f  f32  128      @ 131,072
//   gn_ab f32x2 512     @ 131,584
//   lp    f32  131,072  @ 1,048,576   [half][bh][l] l-partials (512 KB)
//   Qt    bf16 2,097,152 @ 8,388,608   [b*H+h][l][32]
//   Kt    bf16 2,097,152 @ 12,582,912  [b*H+h][l][32]
//   Vb    fp16 2,097,152 @ 16,777,216  [b*H+h][32][l]
//   ot    bf16 2,097,152 @ 20,971,520  [b][l][128]
//   op    f32  4,194,304 @ 25,165,824  [half][b][l][128] O-partials (16 MB, ends 41.9 MB)

#define B_ 4
#define C_ 128
#define L_ 4096
#define H_ 4
#define HD_ 32
#define NG_ 32
#define CPG_ 4
#define EPS_ 1e-5f
#define QKSCALE_ 0.5050097650430367f  // 32^(-1/4) * sqrt(log2 e)

typedef __attribute__((ext_vector_type(8))) short bf16x8;
typedef __attribute__((ext_vector_type(8))) unsigned short u16x8;
typedef __attribute__((ext_vector_type(4))) float f32x4;
typedef __attribute__((ext_vector_type(2))) _Float16 f16x2;
typedef __attribute__((ext_vector_type(4))) _Float16 f16x4;

#if __has_builtin(__builtin_amdgcn_exp2f)
#define EXP2F(x) __builtin_amdgcn_exp2f(x)
#else
#define EXP2F(x) exp2f(x)
#endif

// __has_builtin(amdgcn) is FALSE in the host pass but raw calls parse in device code.
#define MFMA_PV(a, b, c) __builtin_amdgcn_mfma_f32_16x16x16f16((a), (b), (c), 0, 0, 0)

__device__ __forceinline__ float bu2f(unsigned short u) {
  return __builtin_bit_cast(float, (unsigned int)(((unsigned int)u) << 16));
}
__device__ __forceinline__ unsigned short f2bu(float f) {
  unsigned int u = __builtin_bit_cast(unsigned int, f);
  unsigned int r = (u + 0x7fffu + ((u >> 16) & 1u)) >> 16;  // RNE
  return (unsigned short)r;
}
__device__ __forceinline__ float4 u42f4(ushort4 u) {
  return make_float4(bu2f(u.x), bu2f(u.y), bu2f(u.z), bu2f(u.w));
}
__device__ __forceinline__ unsigned int pkbf(float a, float b) {
  return (unsigned int)f2bu(a) | ((unsigned int)f2bu(b) << 16);
}
__device__ __forceinline__ f16x2 pkhf2(float a, float b) {
#if __has_builtin(__builtin_amdgcn_cvt_pkrtz)
  return __builtin_bit_cast(f16x2, __builtin_amdgcn_cvt_pkrtz(a, b));
#else
  f16x2 r;
  r[0] = (_Float16)a;
  r[1] = (_Float16)b;
  return r;
#endif
}
__device__ __forceinline__ unsigned int pkhf(float a, float b) {
  return __builtin_bit_cast(unsigned int, pkhf2(a, b));
}

// fp32-vs-bf16 detection via wave-0 ballot — proven R9.
__device__ __forceinline__ bool detect_fast(const ushort* x) {
  __shared__ int flag_s;
  int t = threadIdx.x;
  if (t < 64) {
    int e = (x[t] >> 7) & 0xFF;
    unsigned long long m = __ballot((e < 64) || (e > 192));
    if (t == 0) flag_s = (__popcll(m) > 4) ? 1 : 0;
  }
  __syncthreads();
  return flag_s != 0;
}

__device__ __forceinline__ float4 ldx4(const void* x, size_t idx, bool f32) {
  if (f32) return *((const float4*)x + (idx >> 2));
  ushort4 u = *((const ushort4*)x + (idx >> 2));
  return u42f4(u);
}

// ---------------------------------------------------------------- GN stats + weight cvt
// Unchanged from R13.
__global__ __launch_bounds__(256) void gn_stats(const void* __restrict__ x,
                                                const void* __restrict__ wq,
                                                const void* __restrict__ wp,
                                                const void* __restrict__ bp,
                                                const void* __restrict__ gm,
                                                const void* __restrict__ bt,
                                                ushort* __restrict__ wq_b,
                                                ushort* __restrict__ wp_b,
                                                float* __restrict__ bp_f,
                                                float2* __restrict__ gn_ab) {
  bool f32 = detect_fast((const ushort*)x);
  int blk = blockIdx.x;
  int t = threadIdx.x;

  if (blk >= 128) {
    int i0 = ((blk - 128) * 256 + t) * 8;
#pragma unroll
    for (int k = 0; k < 8; ++k) {
      int i = i0 + k;
      if (i >= 65664) break;
      if (i < 49152) {
        wq_b[i] = f32 ? f2bu(((const float*)wq)[i]) : ((const ushort*)wq)[i];
      } else if (i < 65536) {
        int off = i - 49152;
        wp_b[off] = f32 ? f2bu(((const float*)wp)[off]) : ((const ushort*)wp)[off];
      } else {
        int off = i - 65536;
        bp_f[off] = f32 ? ((const float*)bp)[off] : bu2f(((const ushort*)bp)[off]);
      }
    }
    return;
  }

  int b = blk >> 5, g = blk & 31;
  size_t base = ((size_t)b * C_ + (size_t)g * CPG_) * L_;

  float s = 0.f, ss = 0.f;
#pragma unroll
  for (int i = 0; i < 16; ++i) {
    size_t e = base + i * 1024 + t * 4;
    float4 f = ldx4(x, e, f32);
    s += f.x + f.y + f.z + f.w;
    ss += f.x * f.x + f.y * f.y + f.z * f.z + f.w * f.w;
  }
#pragma unroll
  for (int m = 32; m >= 1; m >>= 1) {
    s += __shfl_xor(s, m, 64);
    ss += __shfl_xor(ss, m, 64);
  }
  __shared__ float red[4][2];
  int wv = t >> 6;
  if ((t & 63) == 0) { red[wv][0] = s; red[wv][1] = ss; }
  __syncthreads();
  float ts = red[0][0] + red[1][0] + red[2][0] + red[3][0];
  float tss = red[0][1] + red[1][1] + red[2][1] + red[3][1];
  float mu = ts * (1.0f / 16384.0f);
  float var = tss * (1.0f / 16384.0f) - mu * mu;
  float rs = rsqrtf(var + EPS_);

  if (t < CPG_) {
    int gi = g * CPG_ + t;
    float ga = f32 ? ((const float*)gm)[gi] : bu2f(((const ushort*)gm)[gi]);
    float be = f32 ? ((const float*)bt)[gi] : bu2f(((const ushort*)bt)[gi]);
    gn_ab[b * C_ + gi] = make_float2(ga * rs, be - mu * ga * rs);
  }
}

// ---------------------------------------------------------------- QKV GEMM (MFMA, gn inline)
// Unchanged from R13.
__global__ __launch_bounds__(256) void qkv_kernel(const ushort* __restrict__ wq_b,
                                                  const void* __restrict__ x,
                                                  const float2* __restrict__ gn_ab,
                                                  ushort* __restrict__ Qt,
                                                  ushort* __restrict__ Kt,
                                                  ushort* __restrict__ Vb) {
  bool f32 = detect_fast((const ushort*)x);
  __shared__ alignas(16) ushort Hs[64][136];
  __shared__ alignas(16) float Ls[64][69];

  int lx = blockIdx.x, oz = blockIdx.y, b = blockIdx.z;
  int t = threadIdx.x;
  int w = t >> 6, lane = t & 63, l16 = lane & 15, q = lane >> 4, q8 = q * 8;

  {
    int u = t & 63, lh = (t >> 6) * 16;
    int c0 = 2 * u;
    float2 ab0 = gn_ab[b * C_ + c0];
    float2 ab1 = gn_ab[b * C_ + c0 + 1];
    size_t xo = ((size_t)b * C_ + c0) * L_ + (size_t)lx * 64 + lh;
#pragma unroll
    for (int j = 0; j < 4; ++j) {
      float4 f0 = ldx4(x, xo + j * 4, f32);
      float4 f1 = ldx4(x, xo + L_ + j * 4, f32);
      float n0[4] = {f0.x * ab0.x + ab0.y, f0.y * ab0.x + ab0.y,
                     f0.z * ab0.x + ab0.y, f0.w * ab0.x + ab0.y};
      float n1[4] = {f1.x * ab1.x + ab1.y, f1.y * ab1.x + ab1.y,
                     f1.z * ab1.x + ab1.y, f1.w * ab1.x + ab1.y};
#pragma unroll
      for (int k = 0; k < 4; ++k)
        *(unsigned int*)&Hs[lh + j * 4 + k][c0] = pkbf(n0[k], n1[k]);
    }
  }
  __syncthreads();

  for (int j = 0; j < 2; ++j) {
    int oy = oz * 2 + j;
    const ushort* wg = wq_b + (size_t)(oy * 64 + w * 16 + l16) * C_;

    f32x4 acc[4] = {{0.f, 0.f, 0.f, 0.f}, {0.f, 0.f, 0.f, 0.f},
                    {0.f, 0.f, 0.f, 0.f}, {0.f, 0.f, 0.f, 0.f}};
#pragma unroll
    for (int kc = 0; kc < 4; ++kc) {
      bf16x8 aw = *(const bf16x8*)(wg + kc * 32 + q8);
#pragma unroll
      for (int nb = 0; nb < 4; ++nb) {
        bf16x8 bh = *(const bf16x8*)&Hs[nb * 16 + l16][kc * 32 + q8];
        acc[nb] = __builtin_amdgcn_mfma_f32_16x16x32_bf16(aw, bh, acc[nb], 0, 0, 0);
      }
    }
    __syncthreads();
#pragma unroll
    for (int nb = 0; nb < 4; ++nb)
#pragma unroll
      for (int r = 0; r < 4; ++r)
        Ls[nb * 16 + l16][w * 16 + 4 * q + r] = acc[nb][r];
    __syncthreads();

#pragma unroll
    for (int hhalf = 0; hhalf < 2; ++hhalf) {
      int hh = oy * 2 + hhalf;
      int type = hh % 3, head = hh / 3;
      size_t bh = (size_t)b * H_ + head;
      if (type == 2) {
        int c_loc = t >> 3, l8 = (t & 7) * 8;
        float v[8];
#pragma unroll
        for (int jj = 0; jj < 8; ++jj) v[jj] = Ls[l8 + jj][hhalf * 32 + c_loc];
        uint4 u;
        u.x = pkhf(v[0], v[1]);
        u.y = pkhf(v[2], v[3]);
        u.z = pkhf(v[4], v[5]);
        u.w = pkhf(v[6], v[7]);
        *(uint4*)(Vb + (bh * 32 + c_loc) * L_ + (size_t)lx * 64 + l8) = u;
      } else {
        ushort* dst = type ? Kt : Qt;
        int l = t >> 2, seg = (t & 3) * 8;
        const float* src = &Ls[l][hhalf * 32 + seg];
        uint4 u;
        u.x = pkbf(src[0] * QKSCALE_, src[1] * QKSCALE_);
        u.y = pkbf(src[2] * QKSCALE_, src[3] * QKSCALE_);
        u.z = pkbf(src[4] * QKSCALE_, src[5] * QKSCALE_);
        u.w = pkbf(src[6] * QKSCALE_, src[7] * QKSCALE_);
        *(uint4*)(dst + ((bh * L_) + lx * 64 + l) * 32 + seg) = u;
      }
    }
  }
}

// ---------------------------------------------------------------- MFMA flash attention
// R14 structure (128-q blocks, 128 s/barrier, register-P PV, ones-MFMA l) with the
// s-range SPLIT over blockIdx.z (2 halves of 2048): 1024 blocks -> 4/CU occupancy.
// Emits UNNORMALIZED fp32 O^T partials + l partials; exact combine downstream.
__global__ __launch_bounds__(256) void attn_kernel(const ushort* __restrict__ Qt,
                                                   const ushort* __restrict__ Kt,
                                                   const ushort* __restrict__ Vb,
                                                   float* __restrict__ op,
                                                   float* __restrict__ lp) {
  __shared__ alignas(16) ushort Ks[2][4096];     // two frag-linear 64x32 K tiles
  __shared__ alignas(16) ushort Vs[2][32][136];  // [c][s0..127] fp16

  int t = threadIdx.x;
  int w = t >> 6, lane = t & 63, l16 = lane & 15, q = lane >> 4;
  int tq0 = blockIdx.x * 128;
  int bh = blockIdx.y;
  int half = blockIdx.z;
  int b = bh >> 2, head = bh & 3;
  const ushort* Qg = Qt + ((size_t)bh * L_ + tq0) * 32;
  const ushort* Kg = Kt + (size_t)bh * L_ * 32;
  const ushort* Vg = Vb + (size_t)bh * 32 * L_;

  int s0 = half * 2048;
  int krow = (t & 15) | ((t >> 6) << 4);
  int kq8 = ((t >> 4) & 3) * 8;
  const ushort* kgp = Kg + (size_t)(s0 + krow) * 32 + kq8;
  int vc = t >> 3, vsl = (t & 7) * 8;
  const ushort* vgp = Vg + (size_t)vc * L_ + s0 + vsl;
  int trow = w * 16 + l16;
  int q8 = q * 8, q4 = q * 4;

  bf16x8 qfrag0 = *(const bf16x8*)(Qg + (size_t)trow * 32 + q8);
  bf16x8 qfrag1 = *(const bf16x8*)(Qg + (size_t)(64 + trow) * 32 + q8);
  f16x4 ones;
#pragma unroll
  for (int i = 0; i < 4; ++i) ones[i] = (_Float16)1.0f;

  // prologue: stage both halves of tile 0
  *(uint4*)&Ks[0][t * 8] = *(const uint4*)kgp;
  *(uint4*)&Ks[0][2048 + t * 8] = *(const uint4*)(kgp + 2048);
  *(uint4*)&Vs[0][vc][vsl] = *(const uint4*)vgp;
  *(uint4*)&Vs[0][vc][64 + vsl] = *(const uint4*)(vgp + 64);
  __syncthreads();

  f32x4 aA0 = {0.f, 0.f, 0.f, 0.f}, aB0 = {0.f, 0.f, 0.f, 0.f};
  f32x4 aA1 = {0.f, 0.f, 0.f, 0.f}, aB1 = {0.f, 0.f, 0.f, 0.f};
  f32x4 aL0 = {0.f, 0.f, 0.f, 0.f}, aL1 = {0.f, 0.f, 0.f, 0.f};
  const ushort* kg_n = kgp + 4096;
  const ushort* vg_n = vgp + 128;

#pragma unroll 2
  for (int it = 0; it < 16; ++it) {
    int bc = it & 1;
    if (it < 15) {
      *(uint4*)&Ks[bc ^ 1][t * 8] = *(const uint4*)kg_n;
      *(uint4*)&Ks[bc ^ 1][2048 + t * 8] = *(const uint4*)(kg_n + 2048);
      *(uint4*)&Vs[bc ^ 1][vc][vsl] = *(const uint4*)vg_n;
      *(uint4*)&Vs[bc ^ 1][vc][64 + vsl] = *(const uint4*)(vg_n + 64);
      kg_n += 4096;
      vg_n += 128;
    }

#pragma unroll
    for (int hh2 = 0; hh2 < 2; ++hh2) {
      const ushort* kf = &Ks[bc][hh2 * 2048 + lane * 8];
      bf16x8 ak0 = *(const bf16x8*)(kf);
      bf16x8 ak1 = *(const bf16x8*)(kf + 512);
      bf16x8 ak2 = *(const bf16x8*)(kf + 1024);
      bf16x8 ak3 = *(const bf16x8*)(kf + 1536);
      f32x4 z = {0.f, 0.f, 0.f, 0.f};
      f32x4 sf0[4], sf1[4];
      sf0[0] = __builtin_amdgcn_mfma_f32_16x16x32_bf16(ak0, qfrag0, z, 0, 0, 0);
      sf0[1] = __builtin_amdgcn_mfma_f32_16x16x32_bf16(ak1, qfrag0, z, 0, 0, 0);
      sf0[2] = __builtin_amdgcn_mfma_f32_16x16x32_bf16(ak2, qfrag0, z, 0, 0, 0);
      sf0[3] = __builtin_amdgcn_mfma_f32_16x16x32_bf16(ak3, qfrag0, z, 0, 0, 0);
      sf1[0] = __builtin_amdgcn_mfma_f32_16x16x32_bf16(ak0, qfrag1, z, 0, 0, 0);
      sf1[1] = __builtin_amdgcn_mfma_f32_16x16x32_bf16(ak1, qfrag1, z, 0, 0, 0);
      sf1[2] = __builtin_amdgcn_mfma_f32_16x16x32_bf16(ak2, qfrag1, z, 0, 0, 0);
      sf1[3] = __builtin_amdgcn_mfma_f32_16x16x32_bf16(ak3, qfrag1, z, 0, 0, 0);

#pragma unroll
      for (int n = 0; n < 4; ++n) {
        f16x4 va0 = *(const f16x4*)&Vs[bc][l16][hh2 * 64 + n * 16 + q4];
        f16x4 va1 = *(const f16x4*)&Vs[bc][16 + l16][hh2 * 64 + n * 16 + q4];
        {  // q-tile 0
          float p0 = EXP2F(sf0[n][0]);
          float p1 = EXP2F(sf0[n][1]);
          float p2 = EXP2F(sf0[n][2]);
          float p3 = EXP2F(sf0[n][3]);
          f16x2 e01 = pkhf2(p0, p1);
          f16x2 e23 = pkhf2(p2, p3);
          f16x4 pb = __builtin_shufflevector(e01, e23, 0, 1, 2, 3);
          aA0 = MFMA_PV(va0, pb, aA0);
          aB0 = MFMA_PV(va1, pb, aB0);
          aL0 = MFMA_PV(ones, pb, aL0);
        }
        {  // q-tile 1
          float p0 = EXP2F(sf1[n][0]);
          float p1 = EXP2F(sf1[n][1]);
          float p2 = EXP2F(sf1[n][2]);
          float p3 = EXP2F(sf1[n][3]);
          f16x2 e01 = pkhf2(p0, p1);
          f16x2 e23 = pkhf2(p2, p3);
          f16x4 pb = __builtin_shufflevector(e01, e23, 0, 1, 2, 3);
          aA1 = MFMA_PV(va0, pb, aA1);
          aB1 = MFMA_PV(va1, pb, aB1);
          aL1 = MFMA_PV(ones, pb, aL1);
        }
      }
    }
    __syncthreads();
  }

  // epilogue: UNNORMALIZED fp32 O^T -> [t][c] via LDS (overlay on Ks), plus l partials.
  // aL rows all equal l[t = w16+l16] -> per-lane scalar, no shuffles.
  __syncthreads();
  float* Ep32 = (float*)&Ks[0][0];  // [64][40] floats = 10240 B
  size_t opBase = (size_t)half * (B_ * L_ * C_) + ((size_t)b * L_ + tq0) * C_ + head * 32;
#pragma unroll
  for (int p = 0; p < 2; ++p) {
    f32x4 vA = p ? aA1 : aA0;
    f32x4 vB = p ? aB1 : aB0;
#pragma unroll
    for (int r = 0; r < 4; ++r) {
      Ep32[trow * 40 + q4 + r] = vA[r];
      Ep32[trow * 40 + 16 + q4 + r] = vB[r];
    }
    if (q == 0)
      lp[((size_t)half * 16 + bh) * L_ + tq0 + p * 64 + trow] = p ? aL1[0] : aL0[0];
    __syncthreads();
    {
      int row = t >> 2, seg = (t & 3) * 8;
      float* dst = op + opBase + (size_t)(p * 64 + row) * C_ + seg;
      *(float4*)dst = *(const float4*)&Ep32[row * 40 + seg];
      *(float4*)(dst + 4) = *(const float4*)&Ep32[row * 40 + seg + 4];
    }
    __syncthreads();
  }
}

// ---------------------------------------------------------------- Combine partials
// ot[b][l][c] = bf16( (op0+op1)[b][l][c] / (lp0+lp1)[head(c)][l] ).  Pure streaming.
__global__ __launch_bounds__(256) void combine_kernel(const float* __restrict__ op,
                                                      const float* __restrict__ lp,
                                                      ushort* __restrict__ ot) {
  int idx = blockIdx.x * 256 + threadIdx.x;  // 8 elems each; 2,097,152 total
  int e0 = idx * 8;
  int c0 = e0 & 127;
  int l = (e0 >> 7) & (L_ - 1);
  int b = e0 >> 19;
  int head = c0 >> 5;
  int bh = b * H_ + head;
  float l1 = lp[(size_t)bh * L_ + l];
  float l2 = lp[(size_t)(16 + bh) * L_ + l];
  float inv = 1.0f / (l1 + l2);
  const float* p0 = op + (size_t)e0;
  const float* p1 = op + (size_t)(B_ * L_ * C_) + e0;
  float4 a0 = *(const float4*)p0;
  float4 a1 = *(const float4*)(p0 + 4);
  float4 b0 = *(const float4*)p1;
  float4 b1 = *(const float4*)(p1 + 4);
  uint4 u;
  u.x = pkbf((a0.x + b0.x) * inv, (a0.y + b0.y) * inv);
  u.y = pkbf((a0.z + b0.z) * inv, (a0.w + b0.w) * inv);
  u.z = pkbf((a1.x + b1.x) * inv, (a1.y + b1.y) * inv);
  u.w = pkbf((a1.z + b1.z) * inv, (a1.w + b1.w) * inv);
  *(uint4*)(ot + e0) = u;
}

// ---------------------------------------------------------------- Proj + bias + residual
// Unchanged from R9/R13.
__global__ __launch_bounds__(256) void proj_kernel(const ushort* __restrict__ wp_b,
                                                   const float* __restrict__ bias,
                                                   const void* __restrict__ x,
                                                   const ushort* __restrict__ ot,
                                                   void* __restrict__ out) {
  bool f32 = detect_fast((const ushort*)x);
  __shared__ alignas(16) float Ls[64][37];

  int lx = blockIdx.x, oy = blockIdx.y, b = blockIdx.z;
  int t = threadIdx.x;
  int w = t >> 6, lane = t & 63, l16 = lane & 15, q = lane >> 4, q8 = q * 8;

  const ushort* wg = wp_b + (size_t)(oy * 64 + w * 16 + l16) * C_;
  const ushort* og = ot + ((size_t)b * L_ + (size_t)lx * 32) * C_;

  f32x4 acc[2] = {{0.f, 0.f, 0.f, 0.f}, {0.f, 0.f, 0.f, 0.f}};
#pragma unroll
  for (int kc = 0; kc < 4; ++kc) {
    bf16x8 aw = *(const bf16x8*)(wg + kc * 32 + q8);
#pragma unroll
    for (int nb = 0; nb < 2; ++nb) {
      bf16x8 bo = *(const bf16x8*)(og + (size_t)(nb * 16 + l16) * C_ + kc * 32 + q8);
      acc[nb] = __builtin_amdgcn_mfma_f32_16x16x32_bf16(aw, bo, acc[nb], 0, 0, 0);
    }
  }
#pragma unroll
  for (int nb = 0; nb < 2; ++nb)
#pragma unroll
    for (int r = 0; r < 4; ++r)
      Ls[w * 16 + 4 * q + r][nb * 16 + l16] = acc[nb][r];
  __syncthreads();

  {
    int o_loc = t >> 2, ls0 = (t & 3) * 8;
    float bv = bias[oy * 64 + o_loc];
    size_t off = ((size_t)b * C_ + oy * 64 + o_loc) * L_ + (size_t)lx * 32 + ls0;
#pragma unroll
    for (int jj = 0; jj < 2; ++jj) {
      float4 xf = ldx4(x, off + jj * 4, f32);
      const float* sp = &Ls[o_loc][ls0 + jj * 4];
      float4 r = make_float4(sp[0] + bv + xf.x, sp[1] + bv + xf.y,
                             sp[2] + bv + xf.z, sp[3] + bv + xf.w);
      if (f32) {
        *(float4*)((float*)out + off + jj * 4) = r;
      } else {
        *(ushort4*)((ushort*)out + off + jj * 4) =
            make_ushort4(f2bu(r.x), f2bu(r.y), f2bu(r.z), f2bu(r.w));
      }
    }
  }
}

// ---------------------------------------------------------------- launch
extern "C" void kernel_launch(void* const* d_in, const int* in_sizes, int n_in,
                              void* d_out, int out_size, void* d_ws, size_t ws_size,
                              hipStream_t stream) {
  const void* x      = d_in[0];
  const void* w_qkv  = d_in[1];
  const void* w_proj = d_in[2];
  const void* b_proj = d_in[3];
  const void* gamma  = d_in[4];
  const void* beta   = d_in[5];

  char* wsb = (char*)d_ws;
  ushort* wq_b  = (ushort*)(wsb + 0);
  ushort* wp_b  = (ushort*)(wsb + 98304);
  float*  bp_f  = (float*)(wsb + 131072);
  float2* gn_ab = (float2*)(wsb + 131584);
  float*  lp    = (float*)(wsb + 1048576);    // 2*16*4096 f32 (512 KB)
  ushort* Qt    = (ushort*)(wsb + 8388608);
  ushort* Kt    = (ushort*)(wsb + 12582912);
  ushort* Vb    = (ushort*)(wsb + 16777216);  // fp16
  ushort* ot    = (ushort*)(wsb + 20971520);
  float*  op    = (float*)(wsb + 25165824);   // 2*4*4096*128 f32 (16 MB)

  gn_stats<<<dim3(161), dim3(256), 0, stream>>>(x, w_qkv, w_proj, b_proj, gamma, beta,
                                                wq_b, wp_b, bp_f, gn_ab);
  qkv_kernel<<<dim3(L_ / 64, 3, B_), dim3(256), 0, stream>>>(wq_b, x, gn_ab, Qt, Kt, Vb);
  attn_kernel<<<dim3(L_ / 128, B_ * H_, 2), dim3(256), 0, stream>>>(Qt, Kt, Vb, op, lp);
  combine_kernel<<<dim3(2097152 / (256 * 8)), dim3(256), 0, stream>>>(op, lp, ot);
  proj_kernel<<<dim3(L_ / 32, C_ / 64, B_), dim3(256), 0, stream>>>(wp_b, bp_f, x, ot, d_out);
}